// Round 14
// baseline (324.716 us; speedup 1.0000x reference)
//
#include <hip/hip_runtime.h>

#define HH 512
#define WW 512
#define NIMG 12
#define RAD 3
#define TW 64
#define TH 32
#define LW (TW + 2*RAD)   // 70
#define RPW 8             // output rows per wave (TH / 4 waves)
#define SLABR (RPW + 6)   // 14: rows in a wave's private window

typedef float v2 __attribute__((ext_vector_type(2)));

#define GPTR const __attribute__((address_space(1))) void*
#define LPTR __attribute__((address_space(3))) void*

// R14: private per-wave slabs (R10 layout) + COUNTED-vmcnt DMA pipeline.
//
// SESSION LEDGER:
//  R1 fuse2 48KB LDS: 256us.   R2 +bounds(256,4): 554us (spill).
//  R3 fuse2 TH=16: 276us.      R4 pi-pair ring: 225.5us.
//  R5 stream+clamp: 363us (spill). R6 stream: 252us. R7 +schedbar: 255.7us.
//  R8 +global_load_lds: 221.3us.  R9 TH=32/RPW=8: 207.0us BEST.
//  R10 barrier-free private slabs + FULL per-wave vmcnt(0) drain: 323us.
//      Diagnosis (revised R14): not the slabs -- the full drain. 16
//      independent waves x 56 loads flood the queue; each wave waited
//      for its LAST load before computing anything (VALUBusy 23%).
//  R11 setprio: null. R12 8-wave blocks: 230us. R13 = R9 revert: 210us
//      (reproduces best; noise band +-1.5%).
//  R14: fix R10 with T4 (counted vmcnt): a wave needs only rows 0..6
//      (its first 28 issues) to start the ring; rows 7..13 land under
//      compute, waited row-by-row with vmcnt(4*(6-jj)). No barrier, no
//      correlated stage/drain/compute phases, waves self-stagger.
//      Waits are conservative (outstanding stores only deepen them ->
//      never under-wait). Edge waves: masked path; counted waits become
//      no-ops (few outstanding vmem) -> branch-free reuse.
//      TRIPWIRE: if total >= 207us, revert to R9 and declare plateau.
//
// NUMERICS CONTRACT (harness-validated R1-R13, absmax 9.77e-4 exactly):
//  - conv = sequential fma over the 7x7 window, (ky,kx) row-major, one
//    accumulator per direction (bit-exact im path vs the fp32 ref replay).
//  - L/R, NW/NE, SW/SE packed as v_pk_fma lanes; lane tap sequences
//    identical to scalar chains. U/D scalar chains, same tap order.
//  - pi[s][d] = {row[tx+d], row[tx+d+3]}: operand pairs of the packed
//    chains -> zero packing movs.
//  - PERT: quadrant decomposition, trees unchanged since prior session.
//  - Staging schedule changes only WHEN bytes arrive, not their values.

// Counted wait before consuming slab row 7+jj (issues are 4/row, row-major;
// vmcnt retires oldest-first [m135]). Conservative vs outstanding stores.
__device__ __forceinline__ void stage_wait(int jj) {
    switch (jj) {
        case 0:  asm volatile("s_waitcnt vmcnt(24)" ::: "memory"); break;
        case 1:  asm volatile("s_waitcnt vmcnt(20)" ::: "memory"); break;
        case 2:  asm volatile("s_waitcnt vmcnt(16)" ::: "memory"); break;
        case 3:  asm volatile("s_waitcnt vmcnt(12)" ::: "memory"); break;
        case 4:  asm volatile("s_waitcnt vmcnt(8)"  ::: "memory"); break;
        case 5:  asm volatile("s_waitcnt vmcnt(4)"  ::: "memory"); break;
        default: asm volatile("s_waitcnt vmcnt(0)"  ::: "memory"); break;
    }
}

template <int NR, int LDW, class F>
__device__ __forceinline__ void ring_pass(
    const float* __restrict__ SI, const float* __restrict__ SP,
    int r0, int tx, F emit)
{
    const float w28 = 1.0f / 28.0f;   // fp32-rounded, as in the ref kernels
    const float w16 = 0.0625f;        // exact
    const v2 w28v = {w28, w28};
    const v2 w16v = {w16, w16};

    v2    pi[7][4];   // pi[slot][d] = {row[tx+d], row[tx+d+3]}
    v2    hlr[7];     // pert row partials {hl, hr}
    float cc[7];      // pert center column

    auto rowload = [&](int slot, int m) {
        const float* rI = SI + m * LDW + tx;
        float w0 = rI[0], w1 = rI[1], w2 = rI[2], w3 = rI[3],
              w4 = rI[4], w5 = rI[5], w6 = rI[6];
        pi[slot][0] = (v2){w0, w3};
        pi[slot][1] = (v2){w1, w4};
        pi[slot][2] = (v2){w2, w5};
        pi[slot][3] = (v2){w3, w6};
        const float* rP = SP + m * LDW + tx;
        float b0 = rP[0], b1 = rP[1], b2 = rP[2], b3 = rP[3],
              b4 = rP[4], b5 = rP[5], b6 = rP[6];
        hlr[slot] = (v2){(b0 + b1) + (b2 + b3), (b3 + b4) + (b5 + b6)};
        cc[slot] = b3;
    };

    #pragma unroll
    for (int m = 0; m < 7; ++m)
        rowload(m, r0 + m);

    #pragma unroll
    for (int jj = 0; jj < NR; ++jj) {
        // ---- im: packed L/R, NW/NE, SW/SE + scalar U, D ----
        v2 aLR = {0.f, 0.f}, aQN = {0.f, 0.f}, aQS = {0.f, 0.f};
        #pragma unroll
        for (int dy = 0; dy < 7; ++dy) {
            const int s = (jj + dy) % 7;
            #pragma unroll
            for (int dx = 0; dx < 4; ++dx)   // L: cols 0..3 | R: cols 3..6
                aLR = __builtin_elementwise_fma(pi[s][dx], w28v, aLR);
        }
        float U = 0.f, Dd = 0.f;
        #pragma unroll
        for (int dy = 0; dy < 4; ++dy) {     // U rows 0..3 | D rows 3..6
            const int su = (jj + dy) % 7;
            const int sd = (jj + dy + 3) % 7;
            // cols 0..6 = pi[0].x pi[1].x pi[2].x pi[3].x pi[1].y pi[2].y pi[3].y
            U = fmaf(pi[su][0].x, w28, U);  U = fmaf(pi[su][1].x, w28, U);
            U = fmaf(pi[su][2].x, w28, U);  U = fmaf(pi[su][3].x, w28, U);
            U = fmaf(pi[su][1].y, w28, U);  U = fmaf(pi[su][2].y, w28, U);
            U = fmaf(pi[su][3].y, w28, U);
            Dd = fmaf(pi[sd][0].x, w28, Dd); Dd = fmaf(pi[sd][1].x, w28, Dd);
            Dd = fmaf(pi[sd][2].x, w28, Dd); Dd = fmaf(pi[sd][3].x, w28, Dd);
            Dd = fmaf(pi[sd][1].y, w28, Dd); Dd = fmaf(pi[sd][2].y, w28, Dd);
            Dd = fmaf(pi[sd][3].y, w28, Dd);
            #pragma unroll
            for (int dx = 0; dx < 4; ++dx) { // NW/NE top rows, SW/SE bottom
                aQN = __builtin_elementwise_fma(pi[su][dx], w16v, aQN);
                aQS = __builtin_elementwise_fma(pi[sd][dx], w16v, aQS);
            }
        }

        const float cI = pi[(jj + 3) % 7][3].x;   // center col 3
        const v2 cI2 = {cI, cI};
        const v2 d01 = aLR - cI2;
        const float d2 = U - cI, d3 = Dd - cI;
        const v2 d45 = aQN - cI2;
        const v2 d67 = aQS - cI2;
        float d[8] = {d01.x, d01.y, d2, d3, d45.x, d45.y, d67.x, d67.y};

        // ---- pert: packed quadrant decomposition (values identical R5) ----
        float e[8];
        const int p0 = (jj + 0) % 7, p1 = (jj + 1) % 7, p2 = (jj + 2) % 7,
                  p3 = (jj + 3) % 7, p4 = (jj + 4) % 7, p5 = (jj + 5) % 7,
                  p6 = (jj + 6) % 7;
        const float cP = cc[p3];
        {
            v2 qN = ((hlr[p0] + hlr[p1]) + (hlr[p2] + hlr[p3])); // (qnw,qne)
            v2 qS = ((hlr[p3] + hlr[p4]) + (hlr[p5] + hlr[p6])); // (qsw,qse)
            float cu = ((cc[p0] + cc[p1]) + (cc[p2] + cc[p3]));
            float cd = ((cc[p3] + cc[p4]) + (cc[p5] + cc[p6]));
            const v2 cP2 = {cP, cP};
            v2 eLR = (qN + qS - hlr[p3]) * w28v - cP2;   // (L, R)
            v2 eQN = qN * w16v - cP2;                    // (NW, NE)
            v2 eQS = qS * w16v - cP2;                    // (SW, SE)
            e[0] = eLR.x;  e[1] = eLR.y;
            e[2] = (qN.x + qN.y - cu) * w28 - cP;        // U
            e[3] = (qS.x + qS.y - cd) * w28 - cP;        // D
            e[4] = eQN.x;  e[5] = eQN.y;
            e[6] = eQS.x;  e[7] = eQS.y;
        }

        // first-index-wins argmin over |d| (jnp.argmin tie-break)
        float bestAbs = fabsf(d[0]);
        float bd = d[0];
        float be = e[0];
        #pragma unroll
        for (int j = 1; j < 8; ++j) {
            float a = fabsf(d[j]);
            bool take = a < bestAbs;
            bestAbs = take ? a : bestAbs;
            bd = take ? d[j] : bd;
            be = take ? e[j] : be;
        }

        emit(jj, cI + bd, cP + be);

        if (jj < NR - 1) {
            stage_wait(jj);               // row r0+jj+7 guaranteed landed
            rowload(jj % 7, r0 + jj + 7);
        }
    }
}

__global__ __launch_bounds__(256) void swf_step(
    const float* __restrict__ im_in, const float* __restrict__ pe_in,
    float* __restrict__ im_out, float* __restrict__ pe_out, int storeIm)
{
    // Private per-wave slabs: no cross-wave LDS sharing -> no barrier.
    __shared__ float sI[4][SLABR * LW];   // 15.7 KB
    __shared__ float sP[4][SLABR * LW];   // 15.7 KB (total 31.4 KB)

    const int tid = threadIdx.x;
    const int tx = tid & 63;
    const int wv = tid >> 6;          // wave id 0..3
    const int x0 = blockIdx.x * TW;
    const int yw = blockIdx.y * TH + wv * RPW;   // wave's first output row
    const size_t base = (size_t)blockIdx.z * (size_t)(HH * WW);
    const float* imb = im_in + base;
    const float* peb = pe_in + base;

    float* slabI = &sI[wv][0];
    float* slabP = &sP[wv][0];

    // Wave's window: rows yw-3 .. yw+RPW+2, cols x0-3 .. x0+66.
    const bool wInterior = (blockIdx.x >= 1) && (blockIdx.x <= 6) &&
                           (yw - RAD >= 0) && (yw + RPW + 2 < HH);
    if (wInterior) {
        // Issue ALL 56 DMA loads row-major (4 per row: imMain, peMain,
        // imTail, peTail). No drain here -- counted waits downstream.
        #pragma unroll
        for (int r = 0; r < SLABR; ++r) {
            const float* gI = imb + (size_t)(yw - RAD + r) * WW + (x0 - RAD);
            const float* gP = peb + (size_t)(yw - RAD + r) * WW + (x0 - RAD);
            __builtin_amdgcn_global_load_lds((GPTR)(gI + tx),
                                             (LPTR)(&slabI[r * LW]), 4, 0, 0);
            __builtin_amdgcn_global_load_lds((GPTR)(gP + tx),
                                             (LPTR)(&slabP[r * LW]), 4, 0, 0);
            if (tx < 6) {
                __builtin_amdgcn_global_load_lds((GPTR)(gI + 64 + tx),
                                                 (LPTR)(&slabI[r * LW + 64]), 4, 0, 0);
                __builtin_amdgcn_global_load_lds((GPTR)(gP + 64 + tx),
                                                 (LPTR)(&slabP[r * LW + 64]), 4, 0, 0);
            }
        }
    } else {
        // Edge path: masked scalar staging with zero padding (per-wave,
        // compiler-synchronized load->ds_write->ds_read within the wave).
        #pragma unroll 1
        for (int r = 0; r < SLABR; ++r) {
            const int gy = yw - RAD + r;
            const bool oky = (unsigned)gy < (unsigned)HH;
            {
                const int gx = x0 - RAD + tx;
                const bool ok = oky && ((unsigned)gx < (unsigned)WW);
                const int gi = gy * WW + gx;
                slabI[r * LW + tx] = ok ? imb[gi] : 0.0f;
                slabP[r * LW + tx] = ok ? peb[gi] : 0.0f;
            }
            if (tx < 6) {
                const int gx = x0 - RAD + 64 + tx;
                const bool ok = oky && ((unsigned)gx < (unsigned)WW);
                const int gi = gy * WW + gx;
                slabI[r * LW + 64 + tx] = ok ? imb[gi] : 0.0f;
                slabP[r * LW + 64 + tx] = ok ? peb[gi] : 0.0f;
            }
        }
    }

    // Rows 0..6 (first 28 issues) landed -> ring prologue can start while
    // rows 7..13 are still in flight. No-op for edge waves (few vmem
    // outstanding). In-order vmcnt retirement guarantees row identity.
    asm volatile("s_waitcnt vmcnt(28)" ::: "memory");

    ring_pass<RPW, LW>(slabI, slabP, 0, tx,
        [&](int jj, float vI, float vP) {
            const size_t gi = base + (size_t)(yw + jj) * WW + (x0 + tx);
            if (storeIm) im_out[gi] = vI;
            pe_out[gi] = vP;
        });
}

extern "C" void kernel_launch(void* const* d_in, const int* in_sizes, int n_in,
                              void* d_out, int out_size, void* d_ws, size_t ws_size,
                              hipStream_t stream) {
    const float* im0 = (const float*)d_in[0];
    const float* pe0 = (const float*)d_in[1];
    float* out = (float*)d_out;

    const size_t npix = (size_t)NIMG * HH * WW;   // 3,145,728
    float* imA = (float*)d_ws;                    // 12.6 MB
    float* imB = imA + npix;                      // 12.6 MB
    float* peA = imB + npix;                      // 12.6 MB (ws total 37.7 MB)
    float* peB = out;  // d_out doubles as the second pert buffer; parity
                       // lands the final (iter-5) pert write in d_out.

    dim3 grid(WW / TW, HH / TH, NIMG);            // 8 x 16 x 12 = 1536 blocks
    dim3 block(256);

    swf_step<<<grid, block, 0, stream>>>(im0, pe0, imA, peA, 1);  // iter 0
    swf_step<<<grid, block, 0, stream>>>(imA, peA, imB, peB, 1);  // iter 1
    swf_step<<<grid, block, 0, stream>>>(imB, peB, imA, peA, 1);  // iter 2
    swf_step<<<grid, block, 0, stream>>>(imA, peA, imB, peB, 1);  // iter 3
    swf_step<<<grid, block, 0, stream>>>(imB, peB, imA, peA, 1);  // iter 4
    // iter 5: im store is dead (result = filtered pert only) -> skip
    swf_step<<<grid, block, 0, stream>>>(imA, peA, imB, out, 0);  // iter 5
}

// Round 15
// 233.703 us; speedup vs baseline: 1.3894x; 1.3894x over previous
//
#include <hip/hip_runtime.h>

#define HH 512
#define WW 512
#define NIMG 12
#define RAD 3
#define TW 64
#define TH 32
#define LW 70             // logical window width (TW + 2*RAD)
#define LWP 72            // padded LDS row stride (16B-multiple: 288B/row)
#define LH (TH + 2*RAD)   // 38
#define RPW 8             // output rows per wave (TH / 4 waves)

typedef float v2 __attribute__((ext_vector_type(2)));

#define GPTR const __attribute__((address_space(1))) void*
#define LPTR __attribute__((address_space(3))) void*

// R15: R9 structure (proven best) + width-16 DMA staging.
//
// SESSION LEDGER:
//  R1 fuse2: 256us. R2 clamp(256,4): 554us spill. R3 fuse2 TH16: 276us.
//  R4 pi-pair ring: 225.5us. R5 stream+clamp: 363us spill.
//  R6 stream: 252us. R7 +sched_barrier: 255.7us.
//  R8 +global_load_lds(4B): 221.3us. R9 TH=32/RPW=8: 207.0us BEST.
//  R10 private slabs + full drain: 323us. R11 setprio: null.
//  R12 8-wave blocks: 230us. R13 = R9: 210us (noise band +-1.5%).
//  R14 private slabs + counted vmcnt: 324.7us == R10. Counted waits
//      changed NOTHING -> the private-slab STRUCTURE is the pathology
//      (occupancy 14-15% both variants; 4 disjoint per-wave DMA streams
//      serialize). Cooperative interleaved staging + one barrier is
//      load-bearing. R10/R14 arc closed.
//  R15: last untried micro-lever on R9 -- staging DMA width 4 -> 16
//      (guide m93->m97: the biggest staging lever). LDS stride 72,
//      window base x0-4 (16B-aligned: x0%64==0 -> (x0-4)*4 % 16 == 0),
//      one 18-lane width-16 issue per array per row (288B = 72 floats,
//      cols x0-4..x0+67). Ring reads shift +1 col via base pointer.
//      Staging issues halved, 4x fewer DMA queue entries, bytes and
//      window values identical. TRIPWIRE: if >= 207us, final = R9.
//
// NUMERICS CONTRACT (harness-validated R1-R14, absmax 9.77e-4 exactly):
//  - conv = sequential fma over the 7x7 window, (ky,kx) row-major, one
//    accumulator per direction (bit-exact im path vs the fp32 ref replay).
//  - L/R, NW/NE, SW/SE packed as v_pk_fma lanes; lane tap sequences
//    identical to scalar chains. U/D scalar chains, same tap order.
//  - pi[s][d] = {row[tx+d], row[tx+d+3]}: operand pairs of the packed
//    chains -> zero packing movs.
//  - PERT: quadrant decomposition, trees unchanged since prior session.
//  - Staging width/stride change WHERE bytes sit in LDS, not their
//    values: every output row consumes the identical window in
//    identical order -> bit-identical results.
template <int NR, int LDW, class F>
__device__ __forceinline__ void ring_pass(
    const float* __restrict__ SI, const float* __restrict__ SP,
    int r0, int tx, F emit)
{
    const float w28 = 1.0f / 28.0f;   // fp32-rounded, as in the ref kernels
    const float w16 = 0.0625f;        // exact
    const v2 w28v = {w28, w28};
    const v2 w16v = {w16, w16};

    v2    pi[7][4];   // pi[slot][d] = {row[tx+d], row[tx+d+3]}
    v2    hlr[7];     // pert row partials {hl, hr}
    float cc[7];      // pert center column

    auto rowload = [&](int slot, int m) {
        const float* rI = SI + m * LDW + tx;
        float w0 = rI[0], w1 = rI[1], w2 = rI[2], w3 = rI[3],
              w4 = rI[4], w5 = rI[5], w6 = rI[6];
        pi[slot][0] = (v2){w0, w3};
        pi[slot][1] = (v2){w1, w4};
        pi[slot][2] = (v2){w2, w5};
        pi[slot][3] = (v2){w3, w6};
        const float* rP = SP + m * LDW + tx;
        float b0 = rP[0], b1 = rP[1], b2 = rP[2], b3 = rP[3],
              b4 = rP[4], b5 = rP[5], b6 = rP[6];
        hlr[slot] = (v2){(b0 + b1) + (b2 + b3), (b3 + b4) + (b5 + b6)};
        cc[slot] = b3;
    };

    #pragma unroll
    for (int m = 0; m < 7; ++m)
        rowload(m, r0 + m);

    #pragma unroll
    for (int jj = 0; jj < NR; ++jj) {
        // ---- im: packed L/R, NW/NE, SW/SE + scalar U, D ----
        v2 aLR = {0.f, 0.f}, aQN = {0.f, 0.f}, aQS = {0.f, 0.f};
        #pragma unroll
        for (int dy = 0; dy < 7; ++dy) {
            const int s = (jj + dy) % 7;
            #pragma unroll
            for (int dx = 0; dx < 4; ++dx)   // L: cols 0..3 | R: cols 3..6
                aLR = __builtin_elementwise_fma(pi[s][dx], w28v, aLR);
        }
        float U = 0.f, Dd = 0.f;
        #pragma unroll
        for (int dy = 0; dy < 4; ++dy) {     // U rows 0..3 | D rows 3..6
            const int su = (jj + dy) % 7;
            const int sd = (jj + dy + 3) % 7;
            // cols 0..6 = pi[0].x pi[1].x pi[2].x pi[3].x pi[1].y pi[2].y pi[3].y
            U = fmaf(pi[su][0].x, w28, U);  U = fmaf(pi[su][1].x, w28, U);
            U = fmaf(pi[su][2].x, w28, U);  U = fmaf(pi[su][3].x, w28, U);
            U = fmaf(pi[su][1].y, w28, U);  U = fmaf(pi[su][2].y, w28, U);
            U = fmaf(pi[su][3].y, w28, U);
            Dd = fmaf(pi[sd][0].x, w28, Dd); Dd = fmaf(pi[sd][1].x, w28, Dd);
            Dd = fmaf(pi[sd][2].x, w28, Dd); Dd = fmaf(pi[sd][3].x, w28, Dd);
            Dd = fmaf(pi[sd][1].y, w28, Dd); Dd = fmaf(pi[sd][2].y, w28, Dd);
            Dd = fmaf(pi[sd][3].y, w28, Dd);
            #pragma unroll
            for (int dx = 0; dx < 4; ++dx) { // NW/NE top rows, SW/SE bottom
                aQN = __builtin_elementwise_fma(pi[su][dx], w16v, aQN);
                aQS = __builtin_elementwise_fma(pi[sd][dx], w16v, aQS);
            }
        }

        const float cI = pi[(jj + 3) % 7][3].x;   // center col 3
        const v2 cI2 = {cI, cI};
        const v2 d01 = aLR - cI2;
        const float d2 = U - cI, d3 = Dd - cI;
        const v2 d45 = aQN - cI2;
        const v2 d67 = aQS - cI2;
        float d[8] = {d01.x, d01.y, d2, d3, d45.x, d45.y, d67.x, d67.y};

        // ---- pert: packed quadrant decomposition (values identical R5) ----
        float e[8];
        const int p0 = (jj + 0) % 7, p1 = (jj + 1) % 7, p2 = (jj + 2) % 7,
                  p3 = (jj + 3) % 7, p4 = (jj + 4) % 7, p5 = (jj + 5) % 7,
                  p6 = (jj + 6) % 7;
        const float cP = cc[p3];
        {
            v2 qN = ((hlr[p0] + hlr[p1]) + (hlr[p2] + hlr[p3])); // (qnw,qne)
            v2 qS = ((hlr[p3] + hlr[p4]) + (hlr[p5] + hlr[p6])); // (qsw,qse)
            float cu = ((cc[p0] + cc[p1]) + (cc[p2] + cc[p3]));
            float cd = ((cc[p3] + cc[p4]) + (cc[p5] + cc[p6]));
            const v2 cP2 = {cP, cP};
            v2 eLR = (qN + qS - hlr[p3]) * w28v - cP2;   // (L, R)
            v2 eQN = qN * w16v - cP2;                    // (NW, NE)
            v2 eQS = qS * w16v - cP2;                    // (SW, SE)
            e[0] = eLR.x;  e[1] = eLR.y;
            e[2] = (qN.x + qN.y - cu) * w28 - cP;        // U
            e[3] = (qS.x + qS.y - cd) * w28 - cP;        // D
            e[4] = eQN.x;  e[5] = eQN.y;
            e[6] = eQS.x;  e[7] = eQS.y;
        }

        // first-index-wins argmin over |d| (jnp.argmin tie-break)
        float bestAbs = fabsf(d[0]);
        float bd = d[0];
        float be = e[0];
        #pragma unroll
        for (int j = 1; j < 8; ++j) {
            float a = fabsf(d[j]);
            bool take = a < bestAbs;
            bestAbs = take ? a : bestAbs;
            bd = take ? d[j] : bd;
            be = take ? e[j] : be;
        }

        emit(jj, cI + bd, cP + be);

        if (jj < NR - 1)
            rowload(jj % 7, r0 + jj + 7);
    }
}

__global__ __launch_bounds__(256) void swf_step(
    const float* __restrict__ im_in, const float* __restrict__ pe_in,
    float* __restrict__ im_out, float* __restrict__ pe_out, int storeIm)
{
    __shared__ float sI[LH * LWP];   // 10.9 KB
    __shared__ float sP[LH * LWP];   // 10.9 KB (total 21.9 KB)

    const int tid = threadIdx.x;
    const int tx = tid & 63;
    const int wv = tid >> 6;          // wave id 0..3
    const int x0 = blockIdx.x * TW;
    const int y0 = blockIdx.y * TH;
    const size_t base = (size_t)blockIdx.z * (size_t)(HH * WW);
    const float* imb = im_in + base;
    const float* peb = pe_in + base;

    // Interior tiles: stage rows [y0-3, y0+35) x [x0-4, x0+68) with ONE
    // width-16 global_load_lds per array per row: 18 lanes x 16B = 288B
    // = 72 floats, LDS dest = row base + lane*16 (16B-aligned: x0%64==0).
    // Edge tiles: proven masked path (writes padded-row cols 1..70).
    const bool interior = (blockIdx.x >= 1) && (blockIdx.x <= 6) &&
                          (blockIdx.y >= 1) && (blockIdx.y <= (HH/TH - 2));
    if (interior) {
        #pragma unroll 1
        for (int r = wv; r < LH; r += 4) {
            const float* gI = imb + (size_t)(y0 - RAD + r) * WW + (x0 - 4);
            const float* gP = peb + (size_t)(y0 - RAD + r) * WW + (x0 - 4);
            if (tx < 18) {
                __builtin_amdgcn_global_load_lds((GPTR)(gI + tx * 4),
                                                 (LPTR)(&sI[r * LWP]), 16, 0, 0);
                __builtin_amdgcn_global_load_lds((GPTR)(gP + tx * 4),
                                                 (LPTR)(&sP[r * LWP]), 16, 0, 0);
            }
        }
    } else {
        // Masked scalar staging: logical window col c (0..69) = image col
        // x0-3+c, stored at padded-row col 1+c (zero outside image).
        for (int i = tid; i < LH * LW; i += 256) {
            int r = i / LW;
            int c = i - r * LW;
            int gy = y0 - RAD + r;
            int gx = x0 - RAD + c;
            bool ok = ((unsigned)gy < (unsigned)HH) && ((unsigned)gx < (unsigned)WW);
            int gi = gy * WW + gx;
            sI[r * LWP + 1 + c] = ok ? imb[gi] : 0.0f;
            sP[r * LWP + 1 + c] = ok ? peb[gi] : 0.0f;
        }
    }
    __syncthreads();   // compiler emits vmcnt(0)+lgkmcnt(0) drain here

    // Window base = padded col 1 (image col x0-3): bake the +1 shift into
    // the base pointers so ring indexing is unchanged.
    const int r0 = wv * RPW;          // wave's slab: rows r0 .. r0+RPW+5
    ring_pass<RPW, LWP>(&sI[1], &sP[1], r0, tx,
        [&](int jj, float vI, float vP) {
            const size_t gi = base + (size_t)(y0 + r0 + jj) * WW + (x0 + tx);
            if (storeIm) im_out[gi] = vI;
            pe_out[gi] = vP;
        });
}

extern "C" void kernel_launch(void* const* d_in, const int* in_sizes, int n_in,
                              void* d_out, int out_size, void* d_ws, size_t ws_size,
                              hipStream_t stream) {
    const float* im0 = (const float*)d_in[0];
    const float* pe0 = (const float*)d_in[1];
    float* out = (float*)d_out;

    const size_t npix = (size_t)NIMG * HH * WW;   // 3,145,728
    float* imA = (float*)d_ws;                    // 12.6 MB
    float* imB = imA + npix;                      // 12.6 MB
    float* peA = imB + npix;                      // 12.6 MB (ws total 37.7 MB)
    float* peB = out;  // d_out doubles as the second pert buffer; parity
                       // lands the final (iter-5) pert write in d_out.

    dim3 grid(WW / TW, HH / TH, NIMG);            // 8 x 16 x 12 = 1536 blocks
    dim3 block(256);

    swf_step<<<grid, block, 0, stream>>>(im0, pe0, imA, peA, 1);  // iter 0
    swf_step<<<grid, block, 0, stream>>>(imA, peA, imB, peB, 1);  // iter 1
    swf_step<<<grid, block, 0, stream>>>(imB, peB, imA, peA, 1);  // iter 2
    swf_step<<<grid, block, 0, stream>>>(imA, peA, imB, peB, 1);  // iter 3
    swf_step<<<grid, block, 0, stream>>>(imB, peB, imA, peA, 1);  // iter 4
    // iter 5: im store is dead (result = filtered pert only) -> skip
    swf_step<<<grid, block, 0, stream>>>(imA, peA, imB, out, 0);  // iter 5
}

// Round 16
// 207.909 us; speedup vs baseline: 1.5618x; 1.1241x over previous
//
#include <hip/hip_runtime.h>

#define HH 512
#define WW 512
#define NIMG 12
#define RAD 3
#define TW 64
#define TH 32
#define LW (TW + 2*RAD)   // 70
#define LH (TH + 2*RAD)   // 38
#define RPW 8             // output rows per wave (TH / 4 waves)

typedef float v2 __attribute__((ext_vector_type(2)));

#define GPTR const __attribute__((address_space(1))) void*
#define LPTR __attribute__((address_space(3))) void*

// R16 = R9 (FINAL). The measured session optimum: 207.0us (R9), 210.0us
// (R13 re-run; +-1.5% noise band). Baseline at session start: 235.9us.
//
// SESSION LEDGER (complete):
//  R1 fuse2 48KB LDS: 256us.     R2 fuse2+bounds(256,4): 554us (spill).
//  R3 fuse2 TH=16: 276us.        R4 unfused pi-pair ring: 225.5us.
//  R5 stream+bounds(256,8): 363us (spill). R6 stream: 252us.
//  R7 stream+retire-early+sched_barrier: 255.7us.
//  R8 R4 + global_load_lds(width4) interior staging: 221.3us.
//  R9 TH=32/RPW=8 amortization: 207.0us BEST.
//  R10 barrier-free private slabs (full drain): 323us.
//  R11 +setprio: 207.5us null.   R12 8-wave/TH=64 blocks: 230us.
//  R13 = R9 revert: 210.0us (reproduces best).
//  R14 private slabs + counted vmcnt: 324.7us (== R10: the private-slab
//      structure, not the wait discipline, is the pathology).
//  R15 width-16 staging (18-lane): 233.7us (fewer parallel DMA streams
//      beats fewer issues -- parallelism > per-issue efficiency here).
//
// PLATEAU CHARACTERIZATION (why this is final, not a pipe roofline):
//  - VALUBusy ~45-50%, HBM ~8%, bank conflicts 0: no pipe saturated;
//    the wall is latency at a constraint intersection.
//  - Issue floor ~18-19us/dispatch is NUMERICS-PINNED: the grading ref
//    is an fp32 replay requiring exact sequential fma chains; fp32 has
//    no packed-rate doubling on gfx950 (157.3TF vector peak).
//  - Residual ~15us/dispatch is TIER-LOCKED latency: the ~90-VGPR ring
//    live set pins 4 waves/SIMD (tiers halve at 64/128); every route to
//    the 8-wave tier spills (R2/R5) or re-reads LDS at net loss (R6/R7).
//  - The schedule shape (cooperative interleaved staging, ONE barrier,
//    4-wave blocks, width-4 DMA) beat every perturbation in both
//    directions on every axis tried (R10/R12/R14/R15).
//
// NUMERICS CONTRACT (harness-validated R1-R15, absmax 9.77e-4 exactly):
//  - conv = sequential fma over the 7x7 window, (ky,kx) row-major, one
//    accumulator per direction (bit-exact im path vs the fp32 ref replay).
//  - L/R, NW/NE, SW/SE packed as v_pk_fma lanes; each lane's tap sequence
//    identical to the scalar chain. U/D scalar chains, same tap order.
//  - pi[s][d] = {row[tx+d], row[tx+d+3]}: exactly the operand pair of
//    every packed chain -> zero packing movs.
//  - PERT: quadrant decomposition, trees unchanged since prior session.
template <int NR, int LDW, class F>
__device__ __forceinline__ void ring_pass(
    const float* __restrict__ SI, const float* __restrict__ SP,
    int r0, int tx, F emit)
{
    const float w28 = 1.0f / 28.0f;   // fp32-rounded, as in the ref kernels
    const float w16 = 0.0625f;        // exact
    const v2 w28v = {w28, w28};
    const v2 w16v = {w16, w16};

    v2    pi[7][4];   // pi[slot][d] = {row[tx+d], row[tx+d+3]}
    v2    hlr[7];     // pert row partials {hl, hr}
    float cc[7];      // pert center column

    auto rowload = [&](int slot, int m) {
        const float* rI = SI + m * LDW + tx;
        float w0 = rI[0], w1 = rI[1], w2 = rI[2], w3 = rI[3],
              w4 = rI[4], w5 = rI[5], w6 = rI[6];
        pi[slot][0] = (v2){w0, w3};
        pi[slot][1] = (v2){w1, w4};
        pi[slot][2] = (v2){w2, w5};
        pi[slot][3] = (v2){w3, w6};
        const float* rP = SP + m * LDW + tx;
        float b0 = rP[0], b1 = rP[1], b2 = rP[2], b3 = rP[3],
              b4 = rP[4], b5 = rP[5], b6 = rP[6];
        hlr[slot] = (v2){(b0 + b1) + (b2 + b3), (b3 + b4) + (b5 + b6)};
        cc[slot] = b3;
    };

    #pragma unroll
    for (int m = 0; m < 7; ++m)
        rowload(m, r0 + m);

    #pragma unroll
    for (int jj = 0; jj < NR; ++jj) {
        // ---- im: packed L/R, NW/NE, SW/SE + scalar U, D ----
        v2 aLR = {0.f, 0.f}, aQN = {0.f, 0.f}, aQS = {0.f, 0.f};
        #pragma unroll
        for (int dy = 0; dy < 7; ++dy) {
            const int s = (jj + dy) % 7;
            #pragma unroll
            for (int dx = 0; dx < 4; ++dx)   // L: cols 0..3 | R: cols 3..6
                aLR = __builtin_elementwise_fma(pi[s][dx], w28v, aLR);
        }
        float U = 0.f, Dd = 0.f;
        #pragma unroll
        for (int dy = 0; dy < 4; ++dy) {     // U rows 0..3 | D rows 3..6
            const int su = (jj + dy) % 7;
            const int sd = (jj + dy + 3) % 7;
            // cols 0..6 = pi[0].x pi[1].x pi[2].x pi[3].x pi[1].y pi[2].y pi[3].y
            U = fmaf(pi[su][0].x, w28, U);  U = fmaf(pi[su][1].x, w28, U);
            U = fmaf(pi[su][2].x, w28, U);  U = fmaf(pi[su][3].x, w28, U);
            U = fmaf(pi[su][1].y, w28, U);  U = fmaf(pi[su][2].y, w28, U);
            U = fmaf(pi[su][3].y, w28, U);
            Dd = fmaf(pi[sd][0].x, w28, Dd); Dd = fmaf(pi[sd][1].x, w28, Dd);
            Dd = fmaf(pi[sd][2].x, w28, Dd); Dd = fmaf(pi[sd][3].x, w28, Dd);
            Dd = fmaf(pi[sd][1].y, w28, Dd); Dd = fmaf(pi[sd][2].y, w28, Dd);
            Dd = fmaf(pi[sd][3].y, w28, Dd);
            #pragma unroll
            for (int dx = 0; dx < 4; ++dx) { // NW/NE top rows, SW/SE bottom
                aQN = __builtin_elementwise_fma(pi[su][dx], w16v, aQN);
                aQS = __builtin_elementwise_fma(pi[sd][dx], w16v, aQS);
            }
        }

        const float cI = pi[(jj + 3) % 7][3].x;   // center col 3
        const v2 cI2 = {cI, cI};
        const v2 d01 = aLR - cI2;
        const float d2 = U - cI, d3 = Dd - cI;
        const v2 d45 = aQN - cI2;
        const v2 d67 = aQS - cI2;
        float d[8] = {d01.x, d01.y, d2, d3, d45.x, d45.y, d67.x, d67.y};

        // ---- pert: packed quadrant decomposition (values identical R5) ----
        float e[8];
        const int p0 = (jj + 0) % 7, p1 = (jj + 1) % 7, p2 = (jj + 2) % 7,
                  p3 = (jj + 3) % 7, p4 = (jj + 4) % 7, p5 = (jj + 5) % 7,
                  p6 = (jj + 6) % 7;
        const float cP = cc[p3];
        {
            v2 qN = ((hlr[p0] + hlr[p1]) + (hlr[p2] + hlr[p3])); // (qnw,qne)
            v2 qS = ((hlr[p3] + hlr[p4]) + (hlr[p5] + hlr[p6])); // (qsw,qse)
            float cu = ((cc[p0] + cc[p1]) + (cc[p2] + cc[p3]));
            float cd = ((cc[p3] + cc[p4]) + (cc[p5] + cc[p6]));
            const v2 cP2 = {cP, cP};
            v2 eLR = (qN + qS - hlr[p3]) * w28v - cP2;   // (L, R)
            v2 eQN = qN * w16v - cP2;                    // (NW, NE)
            v2 eQS = qS * w16v - cP2;                    // (SW, SE)
            e[0] = eLR.x;  e[1] = eLR.y;
            e[2] = (qN.x + qN.y - cu) * w28 - cP;        // U
            e[3] = (qS.x + qS.y - cd) * w28 - cP;        // D
            e[4] = eQN.x;  e[5] = eQN.y;
            e[6] = eQS.x;  e[7] = eQS.y;
        }

        // first-index-wins argmin over |d| (jnp.argmin tie-break)
        float bestAbs = fabsf(d[0]);
        float bd = d[0];
        float be = e[0];
        #pragma unroll
        for (int j = 1; j < 8; ++j) {
            float a = fabsf(d[j]);
            bool take = a < bestAbs;
            bestAbs = take ? a : bestAbs;
            bd = take ? d[j] : bd;
            be = take ? e[j] : be;
        }

        emit(jj, cI + bd, cP + be);

        if (jj < NR - 1)
            rowload(jj % 7, r0 + jj + 7);
    }
}

__global__ __launch_bounds__(256) void swf_step(
    const float* __restrict__ im_in, const float* __restrict__ pe_in,
    float* __restrict__ im_out, float* __restrict__ pe_out, int storeIm)
{
    __shared__ float sI[LH * LW];
    __shared__ float sP[LH * LW];

    const int tid = threadIdx.x;
    const int tx = tid & 63;
    const int wv = tid >> 6;          // wave id 0..3
    const int x0 = blockIdx.x * TW;
    const int y0 = blockIdx.y * TH;
    const size_t base = (size_t)blockIdx.z * (size_t)(HH * WW);
    const float* imb = im_in + base;
    const float* peb = pe_in + base;

    // Interior tiles: full halo'd footprint [y0-3,y0+35)x[x0-3,x0+67)
    // in-bounds -> stage rows direct global->LDS (per-lane global src,
    // wave-uniform LDS base + lane*4). Edge tiles: proven masked path.
    const bool interior = (blockIdx.x >= 1) && (blockIdx.x <= 6) &&
                          (blockIdx.y >= 1) && (blockIdx.y <= (HH/TH - 2));
    if (interior) {
        #pragma unroll 1
        for (int r = wv; r < LH; r += 4) {
            const float* gI = imb + (size_t)(y0 - RAD + r) * WW + (x0 - RAD);
            const float* gP = peb + (size_t)(y0 - RAD + r) * WW + (x0 - RAD);
            __builtin_amdgcn_global_load_lds((GPTR)(gI + tx),
                                             (LPTR)(&sI[r * LW]), 4, 0, 0);
            __builtin_amdgcn_global_load_lds((GPTR)(gP + tx),
                                             (LPTR)(&sP[r * LW]), 4, 0, 0);
            if (tx < 6) {
                __builtin_amdgcn_global_load_lds((GPTR)(gI + 64 + tx),
                                                 (LPTR)(&sI[r * LW + 64]), 4, 0, 0);
                __builtin_amdgcn_global_load_lds((GPTR)(gP + 64 + tx),
                                                 (LPTR)(&sP[r * LW + 64]), 4, 0, 0);
            }
        }
    } else {
        for (int i = tid; i < LH * LW; i += 256) {
            int r = i / LW;
            int c = i - r * LW;
            int gy = y0 - RAD + r;
            int gx = x0 - RAD + c;
            bool ok = ((unsigned)gy < (unsigned)HH) && ((unsigned)gx < (unsigned)WW);
            int gi = gy * WW + gx;
            sI[i] = ok ? imb[gi] : 0.0f;
            sP[i] = ok ? peb[gi] : 0.0f;
        }
    }
    __syncthreads();   // compiler emits vmcnt(0)+lgkmcnt(0) drain here

    const int r0 = wv * RPW;          // wave's slab: rows r0 .. r0+RPW+5
    ring_pass<RPW, LW>(&sI[0], &sP[0], r0, tx,
        [&](int jj, float vI, float vP) {
            const size_t gi = base + (size_t)(y0 + r0 + jj) * WW + (x0 + tx);
            if (storeIm) im_out[gi] = vI;
            pe_out[gi] = vP;
        });
}

extern "C" void kernel_launch(void* const* d_in, const int* in_sizes, int n_in,
                              void* d_out, int out_size, void* d_ws, size_t ws_size,
                              hipStream_t stream) {
    const float* im0 = (const float*)d_in[0];
    const float* pe0 = (const float*)d_in[1];
    float* out = (float*)d_out;

    const size_t npix = (size_t)NIMG * HH * WW;   // 3,145,728
    float* imA = (float*)d_ws;                    // 12.6 MB
    float* imB = imA + npix;                      // 12.6 MB
    float* peA = imB + npix;                      // 12.6 MB (ws total 37.7 MB)
    float* peB = out;  // d_out doubles as the second pert buffer; parity
                       // lands the final (iter-5) pert write in d_out.

    dim3 grid(WW / TW, HH / TH, NIMG);            // 8 x 16 x 12 = 1536 blocks
    dim3 block(256);

    swf_step<<<grid, block, 0, stream>>>(im0, pe0, imA, peA, 1);  // iter 0
    swf_step<<<grid, block, 0, stream>>>(imA, peA, imB, peB, 1);  // iter 1
    swf_step<<<grid, block, 0, stream>>>(imB, peB, imA, peA, 1);  // iter 2
    swf_step<<<grid, block, 0, stream>>>(imA, peA, imB, peB, 1);  // iter 3
    swf_step<<<grid, block, 0, stream>>>(imB, peB, imA, peA, 1);  // iter 4
    // iter 5: im store is dead (result = filtered pert only) -> skip
    swf_step<<<grid, block, 0, stream>>>(imA, peA, imB, out, 0);  // iter 5
}